// Round 4
// baseline (94.436 us; speedup 1.0000x reference)
//
#include <hip/hip_runtime.h>
#include <hip/hip_bf16.h>
#include <math.h>

#define N 8192
#define S 32                 // j-slices
#define SLICE (N / S)        // 256 j's per slice
#define IBLK 256             // i's per block

// Reference f32 pipeline (verified absmax 0.0 in R2/R3):
//   i = round((log(512)-log(w))/log(1.2)); di = 128/1.2^i; qx = round(x/di-0.5)
// Field bounds (x,y<2000, w,h in [8,512]): i,j in [0,23] (5 bits), qx,qy in
// [0,1035] (11 bits). pack = (j<<27)|(i<<22)|(qy<<11)|qx is a 32-bit code that
// is equality- AND order-isomorphic to the reference's decimal int64 code
// (decimal fields qx + qy*1e4 + i*1e8 + j*1e12 never carry: 1035<1e4, 23<1e4).
__device__ __forceinline__ unsigned pack_code(float x, float y, float w, float h) {
    const float LOG_ALPHA = (float)log((double)1.2f);
    const float LOGW0     = (float)log(512.0);
    float i_f = rintf((LOGW0 - (float)log((double)w)) / LOG_ALPHA);
    float j_f = rintf((LOGW0 - (float)log((double)h)) / LOG_ALPHA);
    float pi  = (float)pow((double)1.2f, (double)i_f);
    float pj  = (float)pow((double)1.2f, (double)j_f);
    float qx  = rintf(x / (128.0f / pi) - 0.5f);
    float qy  = rintf(y / (128.0f / pj) - 0.5f);
    return ((unsigned)(int)j_f << 27) | ((unsigned)(int)i_f << 22)
         | ((unsigned)(int)qy << 11) | (unsigned)(int)qx;
}

// K1: code32[i], pairw[i] = (code<<32)|conf_bits (conf in [0,1) -> bit pattern
// is order-monotone). Zero lose & out (padded unique cols must be 0).
__global__ void k_codes(const float4* __restrict__ rects,
                        const float* __restrict__ conf,
                        unsigned* __restrict__ code32,
                        unsigned long long* __restrict__ pairw,
                        int* __restrict__ lose,
                        int* __restrict__ out) {
    int t = blockIdx.x * blockDim.x + threadIdx.x;
    float4 r = rects[t];
    unsigned c = pack_code(r.x, r.y, r.z, r.w);
    code32[t] = c;
    pairw[t]  = ((unsigned long long)c << 32) | (unsigned long long)__float_as_uint(conf[t]);
    lose[t] = 0;
    out[t]  = 0;
}

// K2: thread (i, slice) scans its 256 j's via wave-uniform scalar loads
// (pairw[jbase+k] is uniform across the wave -> s_load through K$, no LDS).
// j beats i iff same code && (conf_j>conf_i || (conf==conf && j<i)).
__global__ void __launch_bounds__(IBLK)
k_winner(const unsigned long long* __restrict__ pairw, int* __restrict__ lose) {
    int i = blockIdx.x * IBLK + threadIdx.x;
    int jbase = blockIdx.y * SLICE;
    unsigned long long wi = pairw[i];
    unsigned wi_hi = (unsigned)(wi >> 32);
    int l = 0;
    #pragma unroll 16
    for (int k = 0; k < SLICE; ++k) {
        unsigned long long wj = pairw[jbase + k];            // uniform -> s_load
        bool same = (unsigned)(wj >> 32) == wi_hi;
        bool beat = same && ((wj > wi) || ((wj == wi) && (jbase + k < i)));
        l |= (int)beat;
    }
    if (l) atomicOr(&lose[i], 1);                            // rare (losers only)
}

// K3: partial rank: r = #{j in slice : j is winner && code_j < code_i}.
// Losers masked to 0xFFFFFFFF (unreachable code: top j-bits <= 23 < 31).
// Plain coalesced store per (slice, i) — no atomics.
__global__ void __launch_bounds__(IBLK)
k_rank(const unsigned* __restrict__ code32, const int* __restrict__ lose,
       int* __restrict__ rank_part) {
    int i = blockIdx.x * IBLK + threadIdx.x;
    int jbase = blockIdx.y * SLICE;
    unsigned ci = code32[i];
    int r = 0;
    #pragma unroll 16
    for (int k = 0; k < SLICE; ++k) {
        unsigned cj = code32[jbase + k];                     // uniform -> s_load
        int lj = lose[jbase + k];                            // uniform -> s_load
        unsigned val = lj ? 0xFFFFFFFFu : cj;                // scalar cselect
        r += (int)(val < ci);
    }
    rank_part[blockIdx.y * N + i] = r;
}

// K4: winners sum their 32 partials (rank = #unique codes below mine, exactly
// one winner per unique code) and scatter their index.
__global__ void k_scatter(const float* __restrict__ conf,
                          const int* __restrict__ lose,
                          const int* __restrict__ rank_part,
                          int* __restrict__ out) {
    int i = blockIdx.x * blockDim.x + threadIdx.x;
    int r = 0;
    #pragma unroll
    for (int s = 0; s < S; ++s) r += rank_part[s * N + i];   // coalesced rows
    if (lose[i] == 0) {
        // conf==0 edge: all-zero score column -> reference argmax returns 0.
        out[r] = (conf[i] == 0.0f) ? 0 : i;
    }
}

extern "C" void kernel_launch(void* const* d_in, const int* in_sizes, int n_in,
                              void* d_out, int out_size, void* d_ws, size_t ws_size,
                              hipStream_t stream) {
    const float4* rects = (const float4*)d_in[0];   // (8192, 4) f32
    const float*  conf  = (const float*)d_in[1];    // (8192,)  f32
    int* out = (int*)d_out;                         // int32 indices

    char* ws = (char*)d_ws;
    unsigned long long* pairw = (unsigned long long*)ws;          // 64 KiB (8B aligned first)
    unsigned* code32 = (unsigned*)(ws + N * 8);                   // 32 KiB
    int*      lose   = (int*)(ws + N * 8 + N * 4);                // 32 KiB
    int*      rank_part = (int*)(ws + N * 8 + N * 4 + N * 4);     // 1 MiB (32 x N)

    k_codes  <<<N / 256, 256, 0, stream>>>(rects, conf, code32, pairw, lose, out);
    k_winner <<<dim3(N / IBLK, S), IBLK, 0, stream>>>(pairw, lose);
    k_rank   <<<dim3(N / IBLK, S), IBLK, 0, stream>>>(code32, lose, rank_part);
    k_scatter<<<N / 256, 256, 0, stream>>>(conf, lose, rank_part, out);
}

// Round 5
// 88.765 us; speedup vs baseline: 1.0639x; 1.0639x over previous
//
#include <hip/hip_runtime.h>
#include <hip/hip_bf16.h>
#include <math.h>

#define N 8192
#define JS 64                  // j-slices
#define SL (N / JS)            // 128 j's per slice
#define TPB 256                // threads per block
#define IT 4                   // i's per thread
#define IBT (TPB * IT)         // 1024 i's per block
#define NIB (N / IBT)          // 8 i-blocks

// Reference f32 pipeline (verified absmax 0.0 in R2/R3/R4):
//   i = round((log(512)-log(w))/log(1.2)); di = 128/1.2^i; qx = round(x/di-0.5)
// Field bounds: i,j in [0,23] (5 bits), qx,qy in [0,1035] (11 bits).
// pack = (j<<27)|(i<<22)|(qy<<11)|qx is equality- AND order-isomorphic to the
// reference decimal int64 code (fields never carry in decimal: 1035<1e4, 23<1e4).
__device__ __forceinline__ unsigned pack_code(float x, float y, float w, float h) {
    const float LOG_ALPHA = (float)log((double)1.2f);
    const float LOGW0     = (float)log(512.0);
    float i_f = rintf((LOGW0 - (float)log((double)w)) / LOG_ALPHA);
    float j_f = rintf((LOGW0 - (float)log((double)h)) / LOG_ALPHA);
    float pi  = (float)pow((double)1.2f, (double)i_f);
    float pj  = (float)pow((double)1.2f, (double)j_f);
    float qx  = rintf(x / (128.0f / pi) - 0.5f);
    float qy  = rintf(y / (128.0f / pj) - 0.5f);
    return ((unsigned)(int)j_f << 27) | ((unsigned)(int)i_f << 22)
         | ((unsigned)(int)qy << 11) | (unsigned)(int)qx;
}

// K1: pairw[i] = (code<<32)|conf_bits (conf in [0,1) -> bits order-monotone,
// no sign issues). code32 kept separately for the rank pass. Zero lose & out.
__global__ void k_codes(const float4* __restrict__ rects,
                        const float* __restrict__ conf,
                        unsigned* __restrict__ code32,
                        unsigned long long* __restrict__ pairw,
                        int* __restrict__ lose,
                        int* __restrict__ out) {
    int t = blockIdx.x * blockDim.x + threadIdx.x;
    float4 r = rects[t];
    unsigned c = pack_code(r.x, r.y, r.z, r.w);
    code32[t] = c;
    pairw[t]  = ((unsigned long long)c << 32) | (unsigned long long)__float_as_uint(conf[t]);
    lose[t] = 0;
    out[t]  = 0;
}

// K2: i beaten by j iff same code && (conf_j>conf_i || (conf_j==conf_i && j<i)).
// With w=(code<<32)|conf: beat = (wj>wi && wj<bound_i) || (wj==wi && j<i),
// bound_i = (code_i+1)<<32. 4 v_cmp_u64 per compare; mask logic on scalar pipe.
// Each thread covers IT=4 i's per staged j (LDS read amortized 4x, broadcast).
__global__ void __launch_bounds__(TPB)
k_winner(const unsigned long long* __restrict__ pairw, int* __restrict__ lose) {
    __shared__ unsigned long long s_w[SL];
    int t = threadIdx.x;
    int jb = blockIdx.y * SL;
    if (t < SL) s_w[t] = pairw[jb + t];

    int i0 = blockIdx.x * IBT + t;
    unsigned long long wi[IT], bd[IT];
    #pragma unroll
    for (int m = 0; m < IT; ++m) {
        wi[m] = pairw[i0 + m * TPB];
        bd[m] = (wi[m] | 0xFFFFFFFFULL) + 1ULL;     // (code_i+1)<<32
    }
    __syncthreads();

    int l[IT] = {0, 0, 0, 0};
    #pragma unroll 8
    for (int k = 0; k < SL; ++k) {
        unsigned long long wj = s_w[k];             // wave-uniform broadcast
        int jg = jb + k;
        #pragma unroll
        for (int m = 0; m < IT; ++m) {
            l[m] |= (int)(((wj > wi[m]) & (wj < bd[m])) |
                          ((wj == wi[m]) & (jg < i0 + m * TPB)));
        }
    }
    #pragma unroll
    for (int m = 0; m < IT; ++m)
        if (l[m]) atomicOr(&lose[i0 + m * TPB], 1); // rare: losers only
}

// K3: partial rank r = #{j in slice : winner_j && code_j < code_i}.
// Losers pre-masked to 0xFFFFFFFF (> any real code: max code < 0xBD000000),
// so inner loop is 1 ds_read_b32 + (v_cmp + add-carry) per i. No atomics.
__global__ void __launch_bounds__(TPB)
k_rank(const unsigned* __restrict__ code32, const int* __restrict__ lose,
       int* __restrict__ rank_part) {
    __shared__ unsigned s_v[SL];
    int t = threadIdx.x;
    int jb = blockIdx.y * SL;
    if (t < SL) s_v[t] = lose[jb + t] ? 0xFFFFFFFFu : code32[jb + t];

    int i0 = blockIdx.x * IBT + t;
    unsigned ci[IT];
    #pragma unroll
    for (int m = 0; m < IT; ++m) ci[m] = code32[i0 + m * TPB];
    __syncthreads();

    int r[IT] = {0, 0, 0, 0};
    #pragma unroll 8
    for (int k = 0; k < SL; ++k) {
        unsigned vj = s_v[k];                       // wave-uniform broadcast
        #pragma unroll
        for (int m = 0; m < IT; ++m) r[m] += (int)(vj < ci[m]);
    }
    #pragma unroll
    for (int m = 0; m < IT; ++m)
        rank_part[blockIdx.y * N + i0 + m * TPB] = r[m];  // coalesced
}

// K4: winners sum their JS partials (rank = #unique codes below mine; exactly
// one winner per unique code) and scatter their index.
__global__ void k_scatter(const float* __restrict__ conf,
                          const int* __restrict__ lose,
                          const int* __restrict__ rank_part,
                          int* __restrict__ out) {
    int i = blockIdx.x * blockDim.x + threadIdx.x;
    int r = 0;
    #pragma unroll
    for (int s = 0; s < JS; ++s) r += rank_part[s * N + i];  // coalesced rows
    if (lose[i] == 0) {
        // conf==0 edge: all-zero score column -> reference argmax returns 0.
        out[r] = (conf[i] == 0.0f) ? 0 : i;
    }
}

extern "C" void kernel_launch(void* const* d_in, const int* in_sizes, int n_in,
                              void* d_out, int out_size, void* d_ws, size_t ws_size,
                              hipStream_t stream) {
    const float4* rects = (const float4*)d_in[0];   // (8192, 4) f32
    const float*  conf  = (const float*)d_in[1];    // (8192,)  f32
    int* out = (int*)d_out;                         // int32 indices

    char* ws = (char*)d_ws;
    unsigned long long* pairw = (unsigned long long*)ws;      // 64 KiB (8B-aligned first)
    unsigned* code32    = (unsigned*)(ws + N * 8);            // 32 KiB
    int*      lose      = (int*)(ws + N * 12);                // 32 KiB
    int*      rank_part = (int*)(ws + N * 16);                // JS*N*4 = 2 MiB

    k_codes  <<<N / 256, 256, 0, stream>>>(rects, conf, code32, pairw, lose, out);
    k_winner <<<dim3(NIB, JS), TPB, 0, stream>>>(pairw, lose);
    k_rank   <<<dim3(NIB, JS), TPB, 0, stream>>>(code32, lose, rank_part);
    k_scatter<<<N / 256, 256, 0, stream>>>(conf, lose, rank_part, out);
}